// Round 1
// baseline (314.728 us; speedup 1.0000x reference)
//
#include <hip/hip_runtime.h>
#include <stdint.h>

#define B_   8
#define N_   512
#define CE_  16
#define BN_  (B_*N_)   // 4096
#define Q_   4         // i-quarter partials

typedef __attribute__((ext_vector_type(8))) short bf16x8;
typedef __attribute__((ext_vector_type(4))) float f32x4;
typedef __attribute__((ext_vector_type(4))) int   i32x4;

union PackA { i32x4 i; bf16x8 h; };

__device__ __forceinline__ unsigned short f2bf_rne(float f) {
  unsigned u = __float_as_uint(f);
  u += 0x7FFFu + ((u >> 16) & 1u);
  return (unsigned short)(u >> 16);
}

// ---------------- K1: row precompute (m1, m2, base) + Wc/bc ----------------
__global__ __launch_bounds__(256) void k1_pre(
    const float* __restrict__ x,
    const float* __restrict__ W1,  const float* __restrict__ b1,
    const float* __restrict__ W2,  const float* __restrict__ b2,
    const float* __restrict__ Wn,  const float* __restrict__ bn,
    const float* __restrict__ Wo1, const float* __restrict__ bo1,
    const float* __restrict__ Wo2, const float* __restrict__ bo2,
    float* __restrict__ m1, float* __restrict__ m2, float* __restrict__ base,
    float* __restrict__ Wc, float* __restrict__ bc)
{
  const int tid = threadIdx.x;
  if (blockIdx.x == BN_/4) {            // fused tiny block: Wc = Wo2@Wn, bc = Wo2@bn
    for (int idx = tid; idx < 64*64; idx += 256) {
      const int k = idx >> 6, m = idx & 63;
      float acc = 0.f;
      for (int t = 0; t < 64; ++t) acc += Wo2[k*64 + t] * Wn[t*64 + m];
      Wc[idx] = acc;
    }
    if (tid < 64) {
      float acc = 0.f;
      for (int t = 0; t < 64; ++t) acc += Wo2[tid*64 + t] * bn[t];
      bc[tid] = acc;
    }
    return;
  }
  const int r = tid >> 6, m = tid & 63;
  const int row = blockIdx.x*4 + r;
  __shared__ float xs[4][64];
  xs[r][m] = x[(size_t)row*64 + m];
  __syncthreads();
  const float* xr = xs[r];
  float a1 = b1[m], a2 = b2[m], a3 = bo1[m] + bo2[m];
  const float* w1r = W1  + m*64;
  const float* w2r = W2  + m*64;
  const float* w3r = Wo1 + m*64;
  #pragma unroll 8
  for (int c = 0; c < 64; ++c) {
    const float xv = xr[c];
    a1 += xv * w1r[c];
    a2 += xv * w2r[c];
    a3 += xv * w3r[c];
  }
  m1[(size_t)row*64 + m]   = a1;
  m2[(size_t)row*64 + m]   = a2;
  base[(size_t)row*64 + m] = a3;
}

// ---------------- K2: masked edge projection + relu + i-reduction ----------------
// block = 4 waves; block <-> (b, j-tile of 16, i-quarter); wave covers 32 i's.
// MFMA f32_16x16x32_bf16, K padded 16->32 (quads 2,3 hold zeros in A and B).
// A[m=lane&15][k=quad*8+j] (verified layout), C/D: col=lane&15, row=quad*4+reg.
__global__ __launch_bounds__(256) void k2_main(
    const float* __restrict__ edge, const float* __restrict__ adj,
    const float* __restrict__ We,   const float* __restrict__ be,
    const float* __restrict__ m1,   const float* __restrict__ m2,
    float* __restrict__ pS, float* __restrict__ pdeg)
{
  const int tid  = threadIdx.x;
  const int lane = tid & 63;
  const int wid  = tid >> 6;
  const int col  = lane & 15;
  const int quad = lane >> 4;

  const int blk = blockIdx.x;       // 0..1023
  const int q   = blk & 3;          // i-quarter
  const int grp = blk >> 2;         // 0..255
  const int b   = grp >> 5;
  const int j0  = (grp & 31) << 4;
  const int i0  = q*128 + wid*32;

  const i32x4 izero = {0,0,0,0};

  // B fragments = We^T per 16-col chunk; zero for k>=16
  bf16x8 bfr[4];
  #pragma unroll
  for (int c = 0; c < 4; ++c) {
    PackA u; u.i = izero;
    if (quad < 2) {
      const float* wr = We + (c*16 + col)*CE_ + quad*8;
      unsigned p0 = ((unsigned)f2bf_rne(wr[1]) << 16) | f2bf_rne(wr[0]);
      unsigned p1 = ((unsigned)f2bf_rne(wr[3]) << 16) | f2bf_rne(wr[2]);
      unsigned p2 = ((unsigned)f2bf_rne(wr[5]) << 16) | f2bf_rne(wr[4]);
      unsigned p3 = ((unsigned)f2bf_rne(wr[7]) << 16) | f2bf_rne(wr[6]);
      i32x4 v = {(int)p0, (int)p1, (int)p2, (int)p3};
      u.i = v;
    }
    bfr[c] = u.h;
  }

  // m1 fragment (+be), laid out to match C rows j0+quad*4+reg
  f32x4 m1f[4];
  #pragma unroll
  for (int c = 0; c < 4; ++c) {
    const float bev = be[c*16 + col];
    const float* mp = m1 + (size_t)(b*N_ + j0 + quad*4)*64 + c*16 + col;
    m1f[c].x = mp[0]   + bev;
    m1f[c].y = mp[64]  + bev;
    m1f[c].z = mp[128] + bev;
    m1f[c].w = mp[192] + bev;
  }

  const f32x4 fzero = {0.f, 0.f, 0.f, 0.f};
  f32x4 S[4];
  S[0] = fzero; S[1] = fzero; S[2] = fzero; S[3] = fzero;
  f32x4 deg4 = fzero;

  const float* ep  = edge + ((size_t)(b*N_ + i0)*N_ + (j0 + col))*CE_ + quad*8;
  const float* ap  = adj  + (size_t)(b*N_ + i0)*N_ + j0 + quad*4;
  const float* apc = adj  + (size_t)(b*N_ + i0)*N_ + j0 + col;
  const float* m2p = m2   + (size_t)(b*N_ + i0)*64 + col;

  for (int it = 0; it < 32; ++it) {
    // per-lane adjacency gate for this lane's A-row (j = j0+col):
    // if adj==0 the (i,j) contribution is exactly 0 -> skip the edge load.
    const float adjc = apc[0];
    PackA ua; ua.i = izero;
    if (quad < 2 && adjc != 0.f) {
      f32x4 e0 = *(const f32x4*)(ep);
      f32x4 e1 = *(const f32x4*)(ep + 4);
      ua.i.x = (int)__builtin_amdgcn_perm(__float_as_uint(e0.y), __float_as_uint(e0.x), 0x07060302u);
      ua.i.y = (int)__builtin_amdgcn_perm(__float_as_uint(e0.w), __float_as_uint(e0.z), 0x07060302u);
      ua.i.z = (int)__builtin_amdgcn_perm(__float_as_uint(e1.y), __float_as_uint(e1.x), 0x07060302u);
      ua.i.w = (int)__builtin_amdgcn_perm(__float_as_uint(e1.w), __float_as_uint(e1.z), 0x07060302u);
    }
    const f32x4 adj4 = *(const f32x4*)ap;

    #pragma unroll
    for (int c = 0; c < 4; ++c) {
      const float m2v = m2p[c*16];
      f32x4 cin;
      cin.x = m1f[c].x + m2v;
      cin.y = m1f[c].y + m2v;
      cin.z = m1f[c].z + m2v;
      cin.w = m1f[c].w + m2v;
      f32x4 r = __builtin_amdgcn_mfma_f32_16x16x32_bf16(ua.h, bfr[c], cin, 0, 0, 0);
      S[c].x += adj4.x * fmaxf(r.x, 0.f);
      S[c].y += adj4.y * fmaxf(r.y, 0.f);
      S[c].z += adj4.z * fmaxf(r.z, 0.f);
      S[c].w += adj4.w * fmaxf(r.w, 0.f);
    }
    deg4 += adj4;
    ep  += N_ * CE_;
    ap  += N_;
    apc += N_;
    m2p += 64;
  }

  // block reduction across the 4 waves (same (b,jt), different i-chunks)
  __shared__ float red[4][1024];
  __shared__ float redd[4][16];
  #pragma unroll
  for (int c = 0; c < 4; ++c) {
    red[wid][(quad*4 + 0)*64 + c*16 + col] = S[c].x;
    red[wid][(quad*4 + 1)*64 + c*16 + col] = S[c].y;
    red[wid][(quad*4 + 2)*64 + c*16 + col] = S[c].z;
    red[wid][(quad*4 + 3)*64 + c*16 + col] = S[c].w;
  }
  if (col == 0) {
    redd[wid][quad*4 + 0] = deg4.x;
    redd[wid][quad*4 + 1] = deg4.y;
    redd[wid][quad*4 + 2] = deg4.z;
    redd[wid][quad*4 + 3] = deg4.w;
  }
  __syncthreads();

  float* oS = pS + ((size_t)q*BN_ + b*N_ + j0)*64;
  #pragma unroll
  for (int t = 0; t < 4; ++t) {
    const int idx = t*256 + tid;
    oS[idx] = red[0][idx] + red[1][idx] + red[2][idx] + red[3][idx];
  }
  if (tid < 16) {
    pdeg[(size_t)q*BN_ + b*N_ + j0 + tid] =
      redd[0][tid] + redd[1][tid] + redd[2][tid] + redd[3][tid];
  }
}

// ---------------- K3: combine partials + fused projection ----------------
__global__ __launch_bounds__(256) void k3_out(
    const float* __restrict__ pS, const float* __restrict__ pdeg,
    const float* __restrict__ base, const float* __restrict__ Wc,
    const float* __restrict__ bc, float* __restrict__ out)
{
  const int tid = threadIdx.x;
  const int r   = tid >> 6;
  const int k   = tid & 63;
  const int row = blockIdx.x*4 + r;
  __shared__ float sm[4][64];
  float s = 0.f, dr = 0.f;
  #pragma unroll
  for (int q = 0; q < Q_; ++q) {
    s  += pS[((size_t)q*BN_ + row)*64 + k];
    dr += pdeg[(size_t)q*BN_ + row];
  }
  sm[r][k] = s;
  __syncthreads();
  float acc = base[(size_t)row*64 + k] + dr * bc[k];
  const float* wr  = Wc + k*64;
  const float* smr = sm[r];
  #pragma unroll
  for (int m = 0; m < 64; ++m) acc += smr[m] * wr[m];
  out[(size_t)row*64 + k] = acc;
}

// ---------------- launch ----------------
extern "C" void kernel_launch(void* const* d_in, const int* in_sizes, int n_in,
                              void* d_out, int out_size, void* d_ws, size_t ws_size,
                              hipStream_t stream)
{
  const float* x    = (const float*)d_in[0];
  const float* adj  = (const float*)d_in[1];
  const float* edge = (const float*)d_in[2];
  const float* W1   = (const float*)d_in[3];
  const float* b1   = (const float*)d_in[4];
  const float* W2   = (const float*)d_in[5];
  const float* b2   = (const float*)d_in[6];
  const float* We   = (const float*)d_in[7];
  const float* be   = (const float*)d_in[8];
  const float* Wn   = (const float*)d_in[9];
  const float* bn   = (const float*)d_in[10];
  const float* Wo1  = (const float*)d_in[11];
  const float* bo1  = (const float*)d_in[12];
  const float* Wo2  = (const float*)d_in[13];
  const float* bo2  = (const float*)d_in[14];
  float* out = (float*)d_out;

  char* ws = (char*)d_ws;
  float* m1   = (float*)(ws);                                  // 1 MiB
  float* m2   = (float*)(ws + (size_t)(1u<<20));               // 1 MiB
  float* base = (float*)(ws + (size_t)2*(1u<<20));             // 1 MiB
  float* Wc   = (float*)(ws + (size_t)3*(1u<<20));             // 16 KiB
  float* bc   = (float*)(ws + (size_t)3*(1u<<20) + 16384);     // 256 B (padded)
  float* pdeg = (float*)(ws + (size_t)3*(1u<<20) + 17408);     // Q*BN*4 = 64 KiB
  float* pS   = (float*)(ws + (size_t)3*(1u<<20) + 17408 + 65536); // Q*BN*64*4 = 4 MiB
  // total ~7.3 MiB of d_ws

  k1_pre<<<BN_/4 + 1, 256, 0, stream>>>(x, W1, b1, W2, b2, Wn, bn,
                                        Wo1, bo1, Wo2, bo2,
                                        m1, m2, base, Wc, bc);
  k2_main<<<1024, 256, 0, stream>>>(edge, adj, We, be, m1, m2, pS, pdeg);
  k3_out<<<BN_/4, 256, 0, stream>>>(pS, pdeg, base, Wc, bc, out);
}

// Round 2
// 301.237 us; speedup vs baseline: 1.0448x; 1.0448x over previous
//
#include <hip/hip_runtime.h>
#include <stdint.h>

#define B_   8
#define N_   512
#define CE_  16
#define BN_  (B_*N_)   // 4096
#define Q_   8         // i-partition partials (8 blocks/CU for latency hiding)

typedef __attribute__((ext_vector_type(8))) short bf16x8;
typedef __attribute__((ext_vector_type(4))) float f32x4;
typedef __attribute__((ext_vector_type(4))) int   i32x4;

union PackA { i32x4 i; bf16x8 h; };

__device__ __forceinline__ unsigned short f2bf_rne(float f) {
  unsigned u = __float_as_uint(f);
  u += 0x7FFFu + ((u >> 16) & 1u);
  return (unsigned short)(u >> 16);
}

// ---------------- K1: row precompute (m1, m2, base) + Wc/bc ----------------
__global__ __launch_bounds__(256) void k1_pre(
    const float* __restrict__ x,
    const float* __restrict__ W1,  const float* __restrict__ b1,
    const float* __restrict__ W2,  const float* __restrict__ b2,
    const float* __restrict__ Wn,  const float* __restrict__ bn,
    const float* __restrict__ Wo1, const float* __restrict__ bo1,
    const float* __restrict__ Wo2, const float* __restrict__ bo2,
    float* __restrict__ m1, float* __restrict__ m2, float* __restrict__ base,
    float* __restrict__ Wc, float* __restrict__ bc)
{
  const int tid = threadIdx.x;
  if (blockIdx.x == BN_/4) {            // fused tiny block: Wc = Wo2@Wn, bc = Wo2@bn
    for (int idx = tid; idx < 64*64; idx += 256) {
      const int k = idx >> 6, m = idx & 63;
      float acc = 0.f;
      for (int t = 0; t < 64; ++t) acc += Wo2[k*64 + t] * Wn[t*64 + m];
      Wc[idx] = acc;
    }
    if (tid < 64) {
      float acc = 0.f;
      for (int t = 0; t < 64; ++t) acc += Wo2[tid*64 + t] * bn[t];
      bc[tid] = acc;
    }
    return;
  }
  const int r = tid >> 6, m = tid & 63;
  const int row = blockIdx.x*4 + r;
  __shared__ float xs[4][64];
  xs[r][m] = x[(size_t)row*64 + m];
  __syncthreads();
  const float* xr = xs[r];
  float a1 = b1[m], a2 = b2[m], a3 = bo1[m] + bo2[m];
  const float* w1r = W1  + m*64;
  const float* w2r = W2  + m*64;
  const float* w3r = Wo1 + m*64;
  #pragma unroll 8
  for (int c = 0; c < 64; ++c) {
    const float xv = xr[c];
    a1 += xv * w1r[c];
    a2 += xv * w2r[c];
    a3 += xv * w3r[c];
  }
  m1[(size_t)row*64 + m]   = a1;
  m2[(size_t)row*64 + m]   = a2;
  base[(size_t)row*64 + m] = a3;
}

// ---------------- K2: dense edge projection + relu + masked i-reduction ----------------
// block = 4 waves; block <-> (b, j-tile of 16, i-eighth); wave covers 16 i's.
// MFMA f32_16x16x32_bf16, K padded 16->32: B fragment is ZERO for k>=16, so the
// A fragment in quads 2,3 may hold arbitrary finite garbage (mirrored loads) --
// no masking, no branches, fully pipelineable loop body.
// A[m=lane&15][k=quad*8+j], C/D: col=lane&15, row=quad*4+reg (verified round 1).
__global__ __launch_bounds__(256) void k2_main(
    const float* __restrict__ edge, const float* __restrict__ adj,
    const float* __restrict__ We,   const float* __restrict__ be,
    const float* __restrict__ m1,   const float* __restrict__ m2,
    float* __restrict__ pS, float* __restrict__ pdeg)
{
  const int tid  = threadIdx.x;
  const int lane = tid & 63;
  const int wid  = tid >> 6;
  const int col  = lane & 15;
  const int quad = lane >> 4;

  const int blk = blockIdx.x;       // 0..2047
  const int q   = blk & 7;          // i-eighth
  const int grp = blk >> 3;         // 0..255
  const int b   = grp >> 5;
  const int j0  = (grp & 31) << 4;
  const int i0  = q*64 + wid*16;

  const i32x4 izero = {0,0,0,0};

  // B fragments = We^T per 16-col chunk; ZERO for k>=16 (this is what makes
  // the garbage-A trick valid: 0 * finite = 0).
  bf16x8 bfr[4];
  #pragma unroll
  for (int c = 0; c < 4; ++c) {
    PackA u; u.i = izero;
    if (quad < 2) {
      const float* wr = We + (c*16 + col)*CE_ + quad*8;
      unsigned p0 = ((unsigned)f2bf_rne(wr[1]) << 16) | f2bf_rne(wr[0]);
      unsigned p1 = ((unsigned)f2bf_rne(wr[3]) << 16) | f2bf_rne(wr[2]);
      unsigned p2 = ((unsigned)f2bf_rne(wr[5]) << 16) | f2bf_rne(wr[4]);
      unsigned p3 = ((unsigned)f2bf_rne(wr[7]) << 16) | f2bf_rne(wr[6]);
      i32x4 v = {(int)p0, (int)p1, (int)p2, (int)p3};
      u.i = v;
    }
    bfr[c] = u.h;
  }

  // m1 fragment (+be), laid out to match C rows j0+quad*4+reg
  f32x4 m1f[4];
  #pragma unroll
  for (int c = 0; c < 4; ++c) {
    const float bev = be[c*16 + col];
    const float* mp = m1 + (size_t)(b*N_ + j0 + quad*4)*64 + c*16 + col;
    m1f[c].x = mp[0]   + bev;
    m1f[c].y = mp[64]  + bev;
    m1f[c].z = mp[128] + bev;
    m1f[c].w = mp[192] + bev;
  }

  const f32x4 fzero = {0.f, 0.f, 0.f, 0.f};
  f32x4 S[4];
  S[0] = fzero; S[1] = fzero; S[2] = fzero; S[3] = fzero;
  f32x4 deg4 = fzero;

  // all 64 lanes load; quads 2,3 mirror quads 0,1 (finite garbage for A k>=16)
  const float* ep  = edge + ((size_t)(b*N_ + i0)*N_ + (j0 + col))*CE_ + (quad & 1)*8;
  const float* ap  = adj  + (size_t)(b*N_ + i0)*N_ + j0 + quad*4;
  const float* m2p = m2   + (size_t)(b*N_ + i0)*64 + col;

  for (int it = 0; it < 16; ++it) {
    f32x4 e0 = *(const f32x4*)(ep);
    f32x4 e1 = *(const f32x4*)(ep + 4);
    PackA ua;
    ua.i.x = (int)__builtin_amdgcn_perm(__float_as_uint(e0.y), __float_as_uint(e0.x), 0x07060302u);
    ua.i.y = (int)__builtin_amdgcn_perm(__float_as_uint(e0.w), __float_as_uint(e0.z), 0x07060302u);
    ua.i.z = (int)__builtin_amdgcn_perm(__float_as_uint(e1.y), __float_as_uint(e1.x), 0x07060302u);
    ua.i.w = (int)__builtin_amdgcn_perm(__float_as_uint(e1.w), __float_as_uint(e1.z), 0x07060302u);
    const f32x4 adj4 = *(const f32x4*)ap;

    #pragma unroll
    for (int c = 0; c < 4; ++c) {
      const float m2v = m2p[c*16];
      f32x4 cin;
      cin.x = m1f[c].x + m2v;
      cin.y = m1f[c].y + m2v;
      cin.z = m1f[c].z + m2v;
      cin.w = m1f[c].w + m2v;
      f32x4 r = __builtin_amdgcn_mfma_f32_16x16x32_bf16(ua.h, bfr[c], cin, 0, 0, 0);
      S[c].x += adj4.x * fmaxf(r.x, 0.f);
      S[c].y += adj4.y * fmaxf(r.y, 0.f);
      S[c].z += adj4.z * fmaxf(r.z, 0.f);
      S[c].w += adj4.w * fmaxf(r.w, 0.f);
    }
    deg4 += adj4;
    ep  += N_ * CE_;
    ap  += N_;
    m2p += 64;
  }

  // block reduction across the 4 waves (same (b,jt), different i-chunks)
  // row stride 68 floats: quad stride 272 % 32 = 16 -> 2-way bank aliasing (free)
  __shared__ float red[4][16*68];
  __shared__ float redd[4][16];
  #pragma unroll
  for (int c = 0; c < 4; ++c) {
    red[wid][(quad*4 + 0)*68 + c*16 + col] = S[c].x;
    red[wid][(quad*4 + 1)*68 + c*16 + col] = S[c].y;
    red[wid][(quad*4 + 2)*68 + c*16 + col] = S[c].z;
    red[wid][(quad*4 + 3)*68 + c*16 + col] = S[c].w;
  }
  if (col == 0) {
    redd[wid][quad*4 + 0] = deg4.x;
    redd[wid][quad*4 + 1] = deg4.y;
    redd[wid][quad*4 + 2] = deg4.z;
    redd[wid][quad*4 + 3] = deg4.w;
  }
  __syncthreads();

  float* oS = pS + ((size_t)q*BN_ + b*N_ + j0)*64;
  #pragma unroll
  for (int t = 0; t < 4; ++t) {
    const int idx = t*256 + tid;
    const int row = idx >> 6, ch = idx & 63;
    oS[idx] = red[0][row*68 + ch] + red[1][row*68 + ch]
            + red[2][row*68 + ch] + red[3][row*68 + ch];
  }
  if (tid < 16) {
    pdeg[(size_t)q*BN_ + b*N_ + j0 + tid] =
      redd[0][tid] + redd[1][tid] + redd[2][tid] + redd[3][tid];
  }
}

// ---------------- K3: combine partials + fused projection ----------------
__global__ __launch_bounds__(256) void k3_out(
    const float* __restrict__ pS, const float* __restrict__ pdeg,
    const float* __restrict__ base, const float* __restrict__ Wc,
    const float* __restrict__ bc, float* __restrict__ out)
{
  const int tid = threadIdx.x;
  const int r   = tid >> 6;
  const int k   = tid & 63;
  const int row = blockIdx.x*4 + r;
  __shared__ float sm[4][64];
  float s = 0.f, dr = 0.f;
  #pragma unroll
  for (int q = 0; q < Q_; ++q) {
    s  += pS[((size_t)q*BN_ + row)*64 + k];
    dr += pdeg[(size_t)q*BN_ + row];
  }
  sm[r][k] = s;
  __syncthreads();
  float acc = base[(size_t)row*64 + k] + dr * bc[k];
  const float* wr  = Wc + k*64;
  const float* smr = sm[r];
  #pragma unroll
  for (int m = 0; m < 64; ++m) acc += smr[m] * wr[m];
  out[(size_t)row*64 + k] = acc;
}

// ---------------- launch ----------------
extern "C" void kernel_launch(void* const* d_in, const int* in_sizes, int n_in,
                              void* d_out, int out_size, void* d_ws, size_t ws_size,
                              hipStream_t stream)
{
  const float* x    = (const float*)d_in[0];
  const float* adj  = (const float*)d_in[1];
  const float* edge = (const float*)d_in[2];
  const float* W1   = (const float*)d_in[3];
  const float* b1   = (const float*)d_in[4];
  const float* W2   = (const float*)d_in[5];
  const float* b2   = (const float*)d_in[6];
  const float* We   = (const float*)d_in[7];
  const float* be   = (const float*)d_in[8];
  const float* Wn   = (const float*)d_in[9];
  const float* bn   = (const float*)d_in[10];
  const float* Wo1  = (const float*)d_in[11];
  const float* bo1  = (const float*)d_in[12];
  const float* Wo2  = (const float*)d_in[13];
  const float* bo2  = (const float*)d_in[14];
  float* out = (float*)d_out;

  char* ws = (char*)d_ws;
  float* m1   = (float*)(ws);                                  // 1 MiB
  float* m2   = (float*)(ws + (size_t)(1u<<20));               // 1 MiB
  float* base = (float*)(ws + (size_t)2*(1u<<20));             // 1 MiB
  float* Wc   = (float*)(ws + (size_t)3*(1u<<20));             // 16 KiB
  float* bc   = (float*)(ws + (size_t)3*(1u<<20) + 16384);     // 256 B (padded)
  float* pdeg = (float*)(ws + (size_t)3*(1u<<20) + 17408);     // Q*BN*4 = 128 KiB
  float* pS   = (float*)(ws + (size_t)3*(1u<<20) + 17408 + 131072); // Q*BN*64*4 = 8 MiB
  // total ~11.4 MiB of d_ws

  k1_pre<<<BN_/4 + 1, 256, 0, stream>>>(x, W1, b1, W2, b2, Wn, bn,
                                        Wo1, bo1, Wo2, bo2,
                                        m1, m2, base, Wc, bc);
  k2_main<<<2048, 256, 0, stream>>>(edge, adj, We, be, m1, m2, pS, pdeg);
  k3_out<<<BN_/4, 256, 0, stream>>>(pS, pdeg, base, Wc, bc, out);
}